// Round 10
// baseline (114.098 us; speedup 1.0000x reference)
//
#include <hip/hip_runtime.h>

#define EPS 1e-8f

typedef float f32x4 __attribute__((ext_vector_type(4)));

// ---------------------------------------------------------------------------
// Output layout (floats):
//   [0,        65536)      concrete_lower  [64,1024]
//   [65536,    131072)     concrete_upper  [64,1024]
//   [131072,   67239936)   lower_coef      [64,1024,1024] (diag only)
//   [67239936, 134348800)  upper_coef      [64,1024,1024] (diag only)
//   [134348800,134414336)  lower_bias      [64,1024] (zeros)
//   [134414336,134479872)  upper_bias      [64,1024] (mu_upper)
//
// R10: the one untested fill cell — PLAIN (cached) stores + per-block
// CONTIGUOUS 2.1 MB region + zero loads inside the loop (R8 minus its
// dependent-load confound). Plain stores let L2 aggregate full lines into
// long DRAM bursts (rocclr evidence); 256 sequential streams = ~2 per
// channel. Zero region: floats [131072, 134414336) = 33570816 f32x4
// = 256 blocks * 131136 f32x4 (exact; 131136 = 512*256 + 64).
// ---------------------------------------------------------------------------

__global__ void __launch_bounds__(256, 1)
fill_zero_kernel(f32x4* __restrict__ dst) {
    const int PER_BLOCK = 131136;
    f32x4* base = dst + (size_t)blockIdx.x * PER_BLOCK + threadIdx.x;
    const f32x4 z = {0.0f, 0.0f, 0.0f, 0.0f};
#pragma unroll 8
    for (int i = 0; i < 512; ++i) {
        base[i * 256] = z;
    }
    if (threadIdx.x < 64) {
        base[512 * 256] = z;
    }
}

__global__ void diag_small_kernel(const float* __restrict__ lower,
                                  const float* __restrict__ upper,
                                  float* __restrict__ out) {
    const int BN = 65536;  // 64*1024
    int t = blockIdx.x * blockDim.x + threadIdx.x;
    if (t >= 2 * BN) return;
    int rr = t & (BN - 1);       // flat (b, i) index into [64,1024]
    int i  = rr & 1023;          // neuron index => diagonal column
    float l = lower[rr];
    float u = upper[rr];
    bool active   = (l >= 0.0f);
    bool crossing = (l < 0.0f) && (u > 0.0f);
    float lam = crossing ? u / (u - l + EPS) : 0.0f;

    // Diagonal element of lower_coef (t < BN) or upper_coef (t >= BN).
    float v = active ? 1.0f : (t < BN ? 0.0f : lam);
    if (v != 0.0f) {
        out[131072LL + (long long)t * 1024 + i] = v;
    }

    if (t < BN) {
        float mu = crossing ? -lam * l : 0.0f;
        out[t]                  = fmaxf(l, 0.0f);   // concrete_lower
        out[BN + t]             = fmaxf(u, 0.0f);   // concrete_upper
        out[134414336LL + t]    = mu;               // upper_bias
        // lower_bias zeros covered by fill_zero_kernel.
    }
}

extern "C" void kernel_launch(void* const* d_in, const int* in_sizes, int n_in,
                              void* d_out, int out_size, void* d_ws, size_t ws_size,
                              hipStream_t stream) {
    const float* lower = (const float*)d_in[0];
    const float* upper = (const float*)d_in[1];
    float* out = (float*)d_out;

    // Zero both coef tensors + lower_bias: floats [131072, 134414336).
    fill_zero_kernel<<<256, 256, 0, stream>>>((f32x4*)(out + 131072));

    // Scatter diagonals + small outputs (after fill on same stream).
    diag_small_kernel<<<512, 256, 0, stream>>>(lower, upper, out);
}

// Round 11
// 106.059 us; speedup vs baseline: 1.0758x; 1.0758x over previous
//
#include <hip/hip_runtime.h>

#define EPS 1e-8f

typedef float f32x4 __attribute__((ext_vector_type(4)));

// ---------------------------------------------------------------------------
// Output layout (floats):
//   [0,        65536)      concrete_lower  [64,1024]
//   [65536,    131072)     concrete_upper  [64,1024]
//   [131072,   67239936)   lower_coef      [64,1024,1024] (diag only)
//   [67239936, 134348800)  upper_coef      [64,1024,1024] (diag only)
//   [134348800,134414336)  lower_bias      [64,1024] (zeros)
//   [134414336,134479872)  upper_bias      [64,1024] (mu_upper)
//
// R11 = R6 (hipMemsetAsync zero-fill, the only path reaching ~5.8 TB/s
// effective; all 6 hand-rolled fill variants measured 4.1-5.3) + improved
// diagonal scatter: write the FULL 64-byte line containing each diagonal
// element via 4 nontemporal f32x4 stores (diag value + 15 zeros). Full-line
// nt writes avoid the per-line RMW fetch (~8-17 MB of scattered HBM reads
// with worst-case row locality) that 4-byte scatter writes incur.
// ---------------------------------------------------------------------------

__global__ void diag_small_kernel(const float* __restrict__ lower,
                                  const float* __restrict__ upper,
                                  float* __restrict__ out) {
    const int BN = 65536;  // 64*1024
    int t = blockIdx.x * blockDim.x + threadIdx.x;
    if (t >= 2 * BN) return;
    int rr = t & (BN - 1);       // flat (b, i) index into [64,1024]
    int i  = rr & 1023;          // neuron index => diagonal column
    float l = lower[rr];
    float u = upper[rr];
    bool active   = (l >= 0.0f);
    bool crossing = (l < 0.0f) && (u > 0.0f);
    float lam = crossing ? u / (u - l + EPS) : 0.0f;

    // Diagonal element of lower_coef (t < BN) or upper_coef (t >= BN).
    float v = active ? 1.0f : (t < BN ? 0.0f : lam);
    if (v != 0.0f) {
        // Write the whole 64B-aligned line holding the diagonal: value +
        // 15 zeros (those bytes are zero from the memset anyway). Full-line
        // nt stores avoid the RMW line fetch of a 4-byte scatter write.
        const int line0 = i & ~15;           // first float col of the line
        float* lp = out + 131072LL + (long long)t * 1024 + line0;
        const int pos = i - line0;           // 0..15
#pragma unroll
        for (int k = 0; k < 4; ++k) {
            f32x4 z = {0.0f, 0.0f, 0.0f, 0.0f};
            if ((pos >> 2) == k) z[pos & 3] = v;
            __builtin_nontemporal_store(z, (f32x4*)(lp + k * 4));
        }
    }

    if (t < BN) {
        float mu = crossing ? -lam * l : 0.0f;
        out[t]                  = fmaxf(l, 0.0f);   // concrete_lower
        out[BN + t]             = fmaxf(u, 0.0f);   // concrete_upper
        out[134414336LL + t]    = mu;               // upper_bias
        // lower_bias zeros covered by the memset.
    }
}

extern "C" void kernel_launch(void* const* d_in, const int* in_sizes, int n_in,
                              void* d_out, int out_size, void* d_ws, size_t ws_size,
                              hipStream_t stream) {
    const float* lower = (const float*)d_in[0];
    const float* upper = (const float*)d_in[1];
    float* out = (float*)d_out;

    // Zero both coef tensors + lower_bias: floats [131072, 134414336)
    //  = 134283264 floats = 537,133,056 bytes (rocclr fill path).
    hipMemsetAsync(out + 131072, 0, 134283264ULL * sizeof(float), stream);

    // Scatter diagonals (full-line nt) + small outputs.
    diag_small_kernel<<<512, 256, 0, stream>>>(lower, upper, out);
}

// Round 12
// 101.509 us; speedup vs baseline: 1.1240x; 1.0448x over previous
//
#include <hip/hip_runtime.h>

#define EPS 1e-8f

// ---------------------------------------------------------------------------
// Output layout (floats):
//   [0,        65536)      concrete_lower  [64,1024]
//   [65536,    131072)     concrete_upper  [64,1024]
//   [131072,   67239936)   lower_coef      [64,1024,1024] (diag only)
//   [67239936, 134348800)  upper_coef      [64,1024,1024] (diag only)
//   [134348800,134414336)  lower_bias     [64,1024] (zeros)
//   [134414336,134479872)  upper_bias     [64,1024] (mu_upper)
//
// Final structure (R6, best measured = 102.3 us):
//   1) hipMemsetAsync zeroes the contiguous region [131072, 134414336)
//      (both coef tensors + lower_bias) via the rocclr fillBufferAligned
//      path — the only fill measured at ~5.8 TB/s effective on this size
//      (7 hand-rolled variants: 4.1-5.3 TB/s).
//   2) A tiny kernel scatters the 131072 diagonal values (skipping zeros)
//      and computes the four small [64,1024] outputs.
// Write volume 537.9 MB is irreducible (harness re-poisons d_out between
// replays); at 5.8-6.7 TB/s the floor is ~85-95 us. This is the roofline.
// ---------------------------------------------------------------------------

__global__ void diag_small_kernel(const float* __restrict__ lower,
                                  const float* __restrict__ upper,
                                  float* __restrict__ out) {
    const int BN = 65536;  // 64*1024
    int t = blockIdx.x * blockDim.x + threadIdx.x;
    if (t >= 2 * BN) return;
    int rr = t & (BN - 1);       // flat (b, i) index into [64,1024]
    int i  = rr & 1023;          // neuron index => diagonal column
    float l = lower[rr];
    float u = upper[rr];
    bool active   = (l >= 0.0f);
    bool crossing = (l < 0.0f) && (u > 0.0f);
    float lam = crossing ? u / (u - l + EPS) : 0.0f;

    // Diagonal element of lower_coef (t < BN) or upper_coef (t >= BN).
    float v = active ? 1.0f : (t < BN ? 0.0f : lam);
    if (v != 0.0f) {
        out[131072LL + (long long)t * 1024 + i] = v;
    }

    if (t < BN) {
        float mu = crossing ? -lam * l : 0.0f;
        out[t]                  = fmaxf(l, 0.0f);   // concrete_lower
        out[BN + t]             = fmaxf(u, 0.0f);   // concrete_upper
        out[134414336LL + t]    = mu;               // upper_bias
        // lower_bias zeros covered by the memset.
    }
}

extern "C" void kernel_launch(void* const* d_in, const int* in_sizes, int n_in,
                              void* d_out, int out_size, void* d_ws, size_t ws_size,
                              hipStream_t stream) {
    const float* lower = (const float*)d_in[0];
    const float* upper = (const float*)d_in[1];
    float* out = (float*)d_out;

    // Zero both coef tensors + lower_bias: floats [131072, 134414336)
    //  = 134283264 floats = 537,133,056 bytes.
    hipMemsetAsync(out + 131072, 0, 134283264ULL * sizeof(float), stream);

    // Scatter diagonals + small outputs (after memset on same stream).
    diag_small_kernel<<<512, 256, 0, stream>>>(lower, upper, out);
}